// Round 6
// baseline (483.043 us; speedup 1.0000x reference)
//
#include <hip/hip_runtime.h>
#include <stdint.h>
#include <stddef.h>

// ---------------------------------------------------------------------------
// MultiHeadAttention forward, MI355X gfx950.  I/O fp32 (mask int32).
//   conv_w4: 4 weights fp32->bf16 (one launch)
//   mask_pack: mask -> 1 bit/key (u64)
//   gemm_qkv (z=3 fused): Q,K -> [B,H,S,64]; V^T -> [B,H,64,S]; A fp32 read
//     in-kernel with post-barrier register prefetch (loads fly under MFMA).
//   attn: X = softmax(mask(QK^T))V, transposed S^T/O^T, 128-key tiles,
//     no-max softmax in log2 domain, row-sum l via ones-MFMA.
//   gemm_out: out = X @ wo^T + bo -> fp32
// ---------------------------------------------------------------------------

typedef unsigned short ushort_t;
typedef unsigned long long u64;
typedef __attribute__((ext_vector_type(8))) short short8;   // 8 bf16 = 4 VGPRs
typedef __attribute__((ext_vector_type(4))) float floatx4;  // MFMA C/D
typedef __attribute__((ext_vector_type(4))) unsigned short ushort4v;
typedef __attribute__((ext_vector_type(4))) unsigned int uint4v;

#define QSCALE (0.125f * 1.4426950408889634f)  // 1/sqrt(64) * log2(e)

__device__ __forceinline__ ushort_t f2bf(float f) {          // RNE
    union { float ff; unsigned int i; } v; v.ff = f;
    unsigned int u = v.i;
    return (ushort_t)((u + 0x7fffu + ((u >> 16) & 1u)) >> 16);
}
__device__ __forceinline__ unsigned int pack2bf(float a, float b) { // round-half-up
    union { float f; unsigned int i; } ua, ub; ua.f = a; ub.f = b;
    return ((ua.i + 0x8000u) >> 16) | ((ub.i + 0x8000u) & 0xffff0000u);
}
__device__ __forceinline__ float fexp2(float x) {
#if __has_builtin(__builtin_amdgcn_exp2f)
    return __builtin_amdgcn_exp2f(x);
#else
    return exp2f(x);
#endif
}
// async global->LDS, 16B/lane. LDS dest = wave-uniform base + lane*16.
__device__ __forceinline__ void g2l16(const void* g, void* l) {
    __builtin_amdgcn_global_load_lds(
        (const __attribute__((address_space(1))) void*)(uintptr_t)g,
        (__attribute__((address_space(3))) void*)(uint32_t)(uintptr_t)l,
        16, 0, 0);
}

// ---------------------------------------------------------------------------
__global__ __launch_bounds__(256) void conv_w4(
    const float* __restrict__ w0, const float* __restrict__ w1,
    const float* __restrict__ w2, const float* __restrict__ w3,
    ushort_t* __restrict__ out)
{
    const int seg = blockIdx.y;
    const float* src = (seg == 0) ? w0 : (seg == 1) ? w1 : (seg == 2) ? w2 : w3;
    const int i = blockIdx.x * 256 + threadIdx.x;
    const float4 v = ((const float4*)src)[i];
    ushort4v o;
    o.x = f2bf(v.x); o.y = f2bf(v.y); o.z = f2bf(v.z); o.w = f2bf(v.w);
    ((ushort4v*)(out + (size_t)seg * 1024 * 1024))[i] = o;
}

__global__ __launch_bounds__(256) void mask_pack(
    const int* __restrict__ m, u64* __restrict__ out)
{
    const int gid = blockIdx.x * 256 + threadIdx.x;
    const u64 bits = __ballot(m[gid] != 0);
    if ((threadIdx.x & 63) == 0) out[gid >> 6] = bits;
}

// ---------------------------------------------------------------------------
// Fused Q/K/V projection. z = blockIdx.z selects {q,k,v}. A fp32 direct with
// post-barrier prefetch; W bf16 via g2l16. Tile 128x128 BK=32, 4 waves 64x64.
// grid (8, 64, 3): id%8 = N-tile -> W-slices L2-resident per XCD.
// z<2 -> bf16 [B,H,S,64] (Q scaled into log2 domain); z==2 -> bf16 [B,H,64,S].
// ---------------------------------------------------------------------------
__global__ __launch_bounds__(256, 3) void gemm_qkv(
    const float* __restrict__ qin, const float* __restrict__ kin,
    const float* __restrict__ vin, const ushort_t* __restrict__ Wall,
    const float* __restrict__ bqp, const float* __restrict__ bkp,
    const float* __restrict__ bvp, ushort_t* __restrict__ Qp,
    ushort_t* __restrict__ Kp, ushort_t* __restrict__ Vtp)
{
    constexpr int K = 1024;
    __shared__ alignas(16) ushort_t As[128 * 32];
    __shared__ alignas(16) ushort_t Bs[128 * 32];

    const int z = blockIdx.z;
    const float* Ain = (z == 0) ? qin : (z == 1) ? kin : vin;
    const ushort_t* W = Wall + (size_t)z * 1024 * 1024;
    const float* bias = (z == 0) ? bqp : (z == 1) ? bkp : bvp;
    const float scale = (z == 0) ? QSCALE : 1.0f;
    ushort_t* Cout = (z == 0) ? Qp : (z == 1) ? Kp : Vtp;

    const int tid  = threadIdx.x;
    const int lane = tid & 63;
    const int w    = tid >> 6;
    const int quad = lane >> 4;
    const int l16  = lane & 15;
    const int wm = w >> 1, wn = w & 1;
    const int bm = blockIdx.y * 128, bn = blockIdx.x * 128;

    // W staging (bf16, swizzled 16B chunks)
    const int ar0 = tid >> 2,         acs0 = ((tid & 3) ^ (ar0 & 3)) * 8;
    const int ar1 = (tid + 256) >> 2, acs1 = ((tid & 3) ^ (ar1 & 3)) * 8;
    const ushort_t* Wst0 = W + (size_t)(bn + ar0) * K + acs0;
    const ushort_t* Wst1 = W + (size_t)(bn + ar1) * K + acs1;

    // A fp32 staging: thread t -> row=t>>1, k-half=(t&1)*16 floats
    const int arow = tid >> 1, ahalf = tid & 1;
    const float* Af = Ain + (size_t)(bm + arow) * K + ahalf * 16;
    const int ac0 = ((2 * ahalf + 0) ^ (arow & 3)) * 8;
    const int ac1 = ((2 * ahalf + 1) ^ (arow & 3)) * 8;

    const int ksw = (quad ^ (l16 & 3)) * 8;
    int asoff[4], bsoff[4];
#pragma unroll
    for (int i = 0; i < 4; i++) {
        asoff[i] = (wm * 64 + i * 16 + l16) * 32 + ksw;
        bsoff[i] = (wn * 64 + i * 16 + l16) * 32 + ksw;
    }

    floatx4 acc[4][4] = {};

    // prefetch A(0)
    float4 fA0, fA1, fA2, fA3;
    {
        const float4* ap = (const float4*)Af;
        fA0 = ap[0]; fA1 = ap[1]; fA2 = ap[2]; fA3 = ap[3];
    }

    for (int kt = 0; kt < K; kt += 32) {
        __syncthreads();
        {
            uint4v c0, c1;
            c0.x = pack2bf(fA0.x, fA0.y); c0.y = pack2bf(fA0.z, fA0.w);
            c0.z = pack2bf(fA1.x, fA1.y); c0.w = pack2bf(fA1.z, fA1.w);
            c1.x = pack2bf(fA2.x, fA2.y); c1.y = pack2bf(fA2.z, fA2.w);
            c1.z = pack2bf(fA3.x, fA3.y); c1.w = pack2bf(fA3.z, fA3.w);
            *(uint4v*)&As[arow * 32 + ac0] = c0;
            *(uint4v*)&As[arow * 32 + ac1] = c1;
        }
        g2l16(Wst0 + kt, &Bs[tid * 8]);
        g2l16(Wst1 + kt, &Bs[(tid + 256) * 8]);
        __syncthreads();

        // prefetch A(kt+1) AFTER the barrier: loads fly under the MFMA phase
        if (kt + 32 < K) {
            const float4* ap = (const float4*)(Af + kt + 32);
            fA0 = ap[0]; fA1 = ap[1]; fA2 = ap[2]; fA3 = ap[3];
        }

        short8 af[4], bf[4];
#pragma unroll
        for (int i = 0; i < 4; i++) af[i] = *(const short8*)&As[asoff[i]];
#pragma unroll
        for (int i = 0; i < 4; i++) bf[i] = *(const short8*)&Bs[bsoff[i]];
#pragma unroll
        for (int mi = 0; mi < 4; mi++)
#pragma unroll
            for (int ni = 0; ni < 4; ni++)
                acc[mi][ni] = __builtin_amdgcn_mfma_f32_16x16x32_bf16(
                    af[mi], bf[ni], acc[mi][ni], 0, 0, 0);
    }

    // epilogue: C/D layout col=lane&15, row=quad*4+reg
#pragma unroll
    for (int ni = 0; ni < 4; ni++) {
        const int n = bn + wn * 64 + ni * 16 + l16;
        const float bv = bias[n];
        const int h = n >> 6, d = n & 63;
#pragma unroll
        for (int mi = 0; mi < 4; mi++) {
            const int mbase = bm + wm * 64 + mi * 16 + quad * 4;
            const int b_ = mbase >> 11;
            if (z == 2) {   // V^T: 4 consecutive s -> one 8B store
                const int s0 = mbase & 2047;
                ushort4v pk;
#pragma unroll
                for (int r = 0; r < 4; r++)
                    pk[r] = f2bf(acc[mi][ni][r] + bv);
                *(ushort4v*)&Cout[(((size_t)(b_ * 16 + h)) * 64 + d) * 2048 + s0] = pk;
            } else {
#pragma unroll
                for (int r = 0; r < 4; r++) {
                    const int s = (mbase + r) & 2047;
                    Cout[(((size_t)(b_ * 16 + h)) * 2048 + s) * 64 + d]
                        = f2bf((acc[mi][ni][r] + bv) * scale);
                }
            }
        }
    }
}

// ---------------------------------------------------------------------------
// Output projection: out[m,n] = X[m,:] @ wo[n,:] + bo, fp32 out. X bf16.
// r4-proven config: g2l16 both operands, grid (8,64), 2 blocks/CU.
// ---------------------------------------------------------------------------
__global__ __launch_bounds__(256, 2) void gemm_out(
    const ushort_t* __restrict__ A, const ushort_t* __restrict__ W,
    const float* __restrict__ bias, float* __restrict__ Cout)
{
    constexpr int N = 1024, K = 1024;
    __shared__ alignas(16) ushort_t As[128 * 32];
    __shared__ alignas(16) ushort_t Bs[128 * 32];

    const int tid  = threadIdx.x;
    const int lane = tid & 63;
    const int w    = tid >> 6;
    const int quad = lane >> 4;
    const int l16  = lane & 15;
    const int wm = w >> 1, wn = w & 1;
    const int bm = blockIdx.y * 128, bn = blockIdx.x * 128;

    const int ar0 = tid >> 2,         acs0 = ((tid & 3) ^ (ar0 & 3)) * 8;
    const int ar1 = (tid + 256) >> 2, acs1 = ((tid & 3) ^ (ar1 & 3)) * 8;

    const ushort_t* Ast0 = A + (size_t)(bm + ar0) * K + acs0;
    const ushort_t* Ast1 = A + (size_t)(bm + ar1) * K + acs1;
    const ushort_t* Wst0 = W + (size_t)(bn + ar0) * K + acs0;
    const ushort_t* Wst1 = W + (size_t)(bn + ar1) * K + acs1;

    const int ksw = (quad ^ (l16 & 3)) * 8;
    int asoff[4], bsoff[4];
#pragma unroll
    for (int i = 0; i < 4; i++) {
        asoff[i] = (wm * 64 + i * 16 + l16) * 32 + ksw;
        bsoff[i] = (wn * 64 + i * 16 + l16) * 32 + ksw;
    }

    floatx4 acc[4][4] = {};

    for (int kt = 0; kt < K; kt += 32) {
        __syncthreads();
        g2l16(Ast0 + kt, &As[tid * 8]);
        g2l16(Ast1 + kt, &As[(tid + 256) * 8]);
        g2l16(Wst0 + kt, &Bs[tid * 8]);
        g2l16(Wst1 + kt, &Bs[(tid + 256) * 8]);
        __syncthreads();

        short8 af[4], bf[4];
#pragma unroll
        for (int i = 0; i < 4; i++) af[i] = *(const short8*)&As[asoff[i]];
#pragma unroll
        for (int i = 0; i < 4; i++) bf[i] = *(const short8*)&Bs[bsoff[i]];
#pragma unroll
        for (int mi = 0; mi < 4; mi++)
#pragma unroll
            for (int ni = 0; ni < 4; ni++)
                acc[mi][ni] = __builtin_amdgcn_mfma_f32_16x16x32_bf16(
                    af[mi], bf[ni], acc[mi][ni], 0, 0, 0);
    }

#pragma unroll
    for (int ni = 0; ni < 4; ni++) {
        const int n = bn + wn * 64 + ni * 16 + l16;
        const float bv = bias[n];
#pragma unroll
        for (int mi = 0; mi < 4; mi++) {
            const int mbase = bm + wm * 64 + mi * 16 + quad * 4;
#pragma unroll
            for (int r = 0; r < 4; r++)
                Cout[(size_t)(mbase + r) * N + n] = acc[mi][ni][r] + bv;
        }
    }
}

// ---------------------------------------------------------------------------
// Flash attention, transposed (S^T = K Q^T: lane = q, regs = 4 consecutive
// keys). 128-key tiles (16 iterations). No-max softmax in log2 domain.
// LDS: Ks 16KB + Vs 16KB + Ps 16KB = 48KB -> 3 blocks/CU.
// ---------------------------------------------------------------------------
__global__ __launch_bounds__(256, 3) void attn(
    const ushort_t* __restrict__ Q,   // [B*H, S, 64] (log2-domain scale)
    const ushort_t* __restrict__ Kk,  // [B*H, S, 64]
    const ushort_t* __restrict__ Vt,  // [B*H, 64, S]
    const u64* __restrict__ mb,       // [B, S, 32] bit-packed mask
    ushort_t* __restrict__ X)         // [B, S, H*64]
{
    constexpr int S = 2048;
    __shared__ alignas(16) ushort_t Ks[128 * 64];
    __shared__ alignas(16) ushort_t Vs[64 * 128];
    __shared__ alignas(16) ushort_t Ps[4][16 * 128];

    const int tid  = threadIdx.x;
    const int lane = tid & 63;
    const int w    = tid >> 6;
    const int quad = lane >> 4;
    const int l16  = lane & 15;
    const int bh = blockIdx.x;          // id%8 = bh%8 -> XCD locality
    const int b  = bh >> 4, h = bh & 15;
    const int qlane = blockIdx.y * 64 + w * 16 + l16;

    // staging: 4 passes of 256 threads, 16B each. idx=tid+256p.
    // Ks row=idx>>3 (128 rows x 8 chunks), chunk col = pos ^ (row&7)
    // Vs row=idx>>4 (64 rows x 16 chunks), col = (pos&8)|((pos&7)^(row&7))
    const ushort_t* Kst[4];
    const ushort_t* Vst[4];
#pragma unroll
    for (int p = 0; p < 4; p++) {
        const int idx = tid + 256 * p;
        const int kr = idx >> 3, kc = (idx & 7) ^ (kr & 7);
        Kst[p] = &Kk[((size_t)bh * S + kr) * 64 + kc * 8];     // + kt*8192
        const int vr = idx >> 4, vpos = idx & 15;
        const int vc = (vpos & 8) | ((vpos & 7) ^ (vr & 7));
        Vst[p] = &Vt[((size_t)bh * 64 + vr) * S + vc * 8];     // + kt*128
    }

    // loop-invariant LDS offsets
    const int swz = l16 & 7;
    int kbase[2];   // Ks frag read (A-op, rows=key): + ni*1024
#pragma unroll
    for (int ks = 0; ks < 2; ks++)
        kbase[ks] = l16 * 64 + (((ks * 4 + quad) ^ swz) * 8);
    int vbase[4];   // Vs frag (+ni*2048) and P frag reads (row stride 128)
#pragma unroll
    for (int ks = 0; ks < 4; ks++) {
        const int c = ks * 4 + quad;
        const int pos = (c & 8) | ((c & 7) ^ swz);
        vbase[ks] = l16 * 128 + pos * 8;
    }
    int pwoff[8];   // P write: 4 consecutive keys -> 8B, swizzled chunk
#pragma unroll
    for (int ni = 0; ni < 8; ni++) {
        const int c = ni * 2 + (quad >> 1);
        const int pos = (c & 8) | ((c & 7) ^ swz);
        pwoff[ni] = l16 * 128 + pos * 8 + (quad & 1) * 4;
    }
    ushort_t* Psw = &Ps[w][0];

    short8 qf[2];
#pragma unroll
    for (int ks = 0; ks < 2; ks++)
        qf[ks] = *(const short8*)&Q[((size_t)bh * S + qlane) * 64 + ks * 32 + quad * 8];

    short8 onesv;
#pragma unroll
    for (int i = 0; i < 8; i++) onesv[i] = (short)0x3F80;  // bf16 1.0

    const u64* mrow = mb + ((size_t)b * S + qlane) * 32;

    floatx4 o[4] = {};
    floatx4 lf = {};

    for (int kt = 0; kt < 16; kt++) {
        __syncthreads();
#pragma unroll
        for (int p = 0; p < 4; p++) {
            g2l16(Kst[p] + kt * 8192, &Ks[(tid + 256 * p) * 8]);
            g2l16(Vst[p] + kt * 128,  &Vs[(tid + 256 * p) * 8]);
        }
        __syncthreads();

        // S^T = K Q^T: 128 key-rows x 16 q-cols
        floatx4 s[8] = {};
#pragma unroll
        for (int ks = 0; ks < 2; ks++)
#pragma unroll
            for (int ni = 0; ni < 8; ni++)
                s[ni] = __builtin_amdgcn_mfma_f32_16x16x32_bf16(
                    *(const short8*)&Ks[kbase[ks] + ni * 1024], qf[ks], s[ni], 0, 0, 0);

        // p = mask ? exp2(s) : 0  (reg r = key ni*16 + quad*4 + r)
        const u64 w0 = mrow[2 * kt], w1 = mrow[2 * kt + 1];
#pragma unroll
        for (int ni = 0; ni < 8; ni++) {
            const unsigned int t =
                (unsigned int)(((ni < 4) ? w0 : w1) >> ((ni & 3) * 16 + quad * 4));
#pragma unroll
            for (int r = 0; r < 4; r++)
                s[ni][r] = (t & (1u << r)) ? fexp2(s[ni][r]) : 0.f;
        }

        // P -> LDS (8x ds_write_b64)
#pragma unroll
        for (int ni = 0; ni < 8; ni++) {
            const unsigned int lo = pack2bf(s[ni][0], s[ni][1]);
            const unsigned int hi = pack2bf(s[ni][2], s[ni][3]);
            *(unsigned long long*)&Psw[pwoff[ni]] =
                ((unsigned long long)hi << 32) | lo;
        }

        // O^T += V^T P ; l += ones^T P
#pragma unroll
        for (int ks = 0; ks < 4; ks++) {
            const short8 pf = *(const short8*)&Psw[vbase[ks]];
            lf = __builtin_amdgcn_mfma_f32_16x16x32_bf16(onesv, pf, lf, 0, 0, 0);
#pragma unroll
            for (int ni = 0; ni < 4; ni++)
                o[ni] = __builtin_amdgcn_mfma_f32_16x16x32_bf16(
                    *(const short8*)&Vs[vbase[ks] + ni * 2048], pf, o[ni], 0, 0, 0);
        }
    }

    // epilogue: lane = q; d = ni*16 + quad*4 + r consecutive -> 8B stores
    const float inv = 1.0f / lf[0];
#pragma unroll
    for (int ni = 0; ni < 4; ni++) {
        ushort4v pk;
#pragma unroll
        for (int r = 0; r < 4; r++) pk[r] = f2bf(o[ni][r] * inv);
        *(ushort4v*)&X[((size_t)b * S + qlane) * 1024 + h * 64 + ni * 16 + quad * 4] = pk;
    }
}

// ---------------------------------------------------------------------------
extern "C" void kernel_launch(void* const* d_in, const int* in_sizes, int n_in,
                              void* d_out, int out_size, void* d_ws, size_t ws_size,
                              hipStream_t stream) {
    const float* q    = (const float*)d_in[0];
    const float* k    = (const float*)d_in[1];
    const float* v    = (const float*)d_in[2];
    const int*   mask = (const int*)d_in[3];
    const float* wq   = (const float*)d_in[4];
    const float* bq   = (const float*)d_in[5];
    const float* wk   = (const float*)d_in[6];
    const float* bk   = (const float*)d_in[7];
    const float* wv   = (const float*)d_in[8];
    const float* bv   = (const float*)d_in[9];
    const float* wo   = (const float*)d_in[10];
    const float* bo   = (const float*)d_in[11];

    const size_t MB = 1024 * 1024;
    uint8_t* ws = (uint8_t*)d_ws;
    ushort_t* Wb   = (ushort_t*)(ws);              //  8 MB: wq,wk,wv,wo bf16
    u64*      mbits= (u64*)(ws + 8 * MB);          //  2 MB
    ushort_t* Qp   = (ushort_t*)(ws + 10 * MB);    // 16 MB
    ushort_t* Kp   = (ushort_t*)(ws + 26 * MB);    // 16 MB
    ushort_t* Vtp  = (ushort_t*)(ws + 42 * MB);    // 16 MB
    ushort_t* Xp   = (ushort_t*)(ws + 58 * MB);    // 16 MB  (total 74 MB)

    dim3 blk(256);
    const int gW = (1024 * 1024) / 1024;
    const int gM = (4 * 2048 * 2048) / 256;

    conv_w4<<<dim3(gW, 4), blk, 0, stream>>>(wq, wk, wv, wo, Wb);
    mask_pack<<<gM, blk, 0, stream>>>(mask, mbits);

    gemm_qkv<<<dim3(8, 64, 3), blk, 0, stream>>>(
        q, k, v, Wb, bq, bk, bv, Qp, Kp, Vtp);

    attn<<<dim3(64, 32), blk, 0, stream>>>(Qp, Kp, Vtp, mbits, Xp);

    gemm_out<<<dim3(8, 64), blk, 0, stream>>>(Xp, Wb + 3 * MB, bo, (float*)d_out);
}